// Round 7
// baseline (190.265 us; speedup 1.0000x reference)
//
#include <hip/hip_runtime.h>
#include <stdint.h>

// SDF closest-point + signed distance, 8192 queries x 2048 tris.
//
// Verified correctness model (R4-R6): harness ref = numpy float32 faithful
// chain; strict IEEE f32, NO fma contraction (pragma inside function), numpy
// op order, np.argmin first-occurrence. cp32 below is the verified DAG.
//
// R7: filter-then-verify. k_scan computes cheap approximate d2 (region-wise
// closed form, precomputed dot constants, no divides) and finds min1/min2.
// If min2 > min1 + margin (margin >= 2*approx error), winner is provably the
// unique exact argmin -> exact epilogue only. Else exact full rescan
// (verified R4 wave-reduce). Exact ties (shared vertices) always flag
// ambiguous -> handled by the exact path.

#define RECA 20   // exact record: a,b,c,ab,ac,cb,pad2
#define RECB 28   // fast record: ab,ac,6 dots,aa,bb,cc,a,n,na,4 invs,pad2
#define CHUNK 256 // faces per LDS chunk in k_scan

__device__ __forceinline__ float safe32(float x) {
    return (fabsf(x) < 1e-12f) ? 1e-12f : x;
}

// ---- exact path (verified bit-exact vs np-f32 in R4/R5/R6) ----
__device__ __forceinline__ float cp32(
    float px, float py, float pz, const float* __restrict__ t,
    float& rx, float& ry, float& rz)
{
#pragma clang fp contract(off)
    float ax  = t[0],  ay  = t[1],  az  = t[2];
    float bx  = t[3],  by  = t[4],  bz  = t[5];
    float cx  = t[6],  cy  = t[7],  cz  = t[8];
    float abx = t[9],  aby = t[10], abz = t[11];
    float acx = t[12], acy = t[13], acz = t[14];
    float cbx = t[15], cby = t[16], cbz = t[17];

    float apx = px - ax, apy = py - ay, apz = pz - az;
    float bpx = px - bx, bpy = py - by, bpz = pz - bz;
    float qpx = px - cx, qpy = py - cy, qpz = pz - cz;

    float d1 = ((abx * apx) + (aby * apy)) + (abz * apz);
    float d2 = ((acx * apx) + (acy * apy)) + (acz * apz);
    float d3 = ((abx * bpx) + (aby * bpy)) + (abz * bpz);
    float d4 = ((acx * bpx) + (acy * bpy)) + (acz * bpz);
    float d5 = ((abx * qpx) + (aby * qpy)) + (abz * qpz);
    float d6 = ((acx * qpx) + (acy * qpy)) + (acz * qpz);

    float vc = (d1 * d4) - (d3 * d2);
    float vb = (d5 * d2) - (d1 * d6);
    float va = (d3 * d6) - (d5 * d4);
    float e1 = d4 - d3;
    float e2 = d5 - d6;

    bool ca  = (d1 <= 0.0f) && (d2 <= 0.0f);
    bool cb_ = (d3 >= 0.0f) && (d4 <= d3);
    bool cab = (vc <= 0.0f) && (d1 >= 0.0f) && (d3 <= 0.0f);
    bool cc_ = (d6 >= 0.0f) && (d5 <= d6);
    bool cac = (vb <= 0.0f) && (d2 >= 0.0f) && (d6 <= 0.0f);
    bool cbc = (va <= 0.0f) && (e1 >= 0.0f) && (e2 >= 0.0f);

    bool tk  = ca;
    bool m_b  = cb_ && !tk;  tk = tk || cb_;
    bool m_ab = cab && !tk;  tk = tk || cab;
    bool m_c  = cc_ && !tk;  tk = tk || cc_;
    bool m_ac = cac && !tk;  tk = tk || cac;
    bool m_bc = cbc && !tk;  tk = tk || cbc;
    bool m_in = !tk;

    float denom_raw = (va + vb) + vc;
    float num1 = m_ab ? d1 : m_ac ? d2 : m_bc ? e1 : m_in ? vb : 0.0f;
    float den1_raw = m_ab ? (d1 - d3) : m_ac ? (d2 - d6)
                   : m_bc ? (e1 + e2) : m_in ? denom_raw : 1.0f;
    float den1  = safe32(den1_raw);
    float denom = safe32(denom_raw);
    float num2  = m_in ? vc : 0.0f;
    float q1 = num1 / den1;
    float q2 = num2 / denom;

    bool sel_b = m_b || m_bc;
    float basx = m_c ? cx : sel_b ? bx : ax;
    float basy = m_c ? cy : sel_b ? by : ay;
    float basz = m_c ? cz : sel_b ? bz : az;

    bool s_ab = m_ab || m_in;
    float t1x = m_bc ? cbx : m_ac ? acx : s_ab ? abx : 0.0f;
    float t1y = m_bc ? cby : m_ac ? acy : s_ab ? aby : 0.0f;
    float t1z = m_bc ? cbz : m_ac ? acz : s_ab ? abz : 0.0f;

    float t2x = m_in ? acx : 0.0f;
    float t2y = m_in ? acy : 0.0f;
    float t2z = m_in ? acz : 0.0f;

    rx = (basx + (t1x * q1)) + (t2x * q2);
    ry = (basy + (t1y * q1)) + (t2y * q2);
    rz = (basz + (t1z * q1)) + (t2z * q2);

    float dx = px - rx, dy = py - ry, dz = pz - rz;
    return ((dx * dx) + (dy * dy)) + (dz * dz);
}

// Exact epilogue (verified R6 k_final body): recompute winner, sign, write.
__device__ __forceinline__ void write_result(
    int q, int widx, const float* __restrict__ trisA,
    float px, float py, float pz, float* __restrict__ out)
{
#pragma clang fp contract(off)
    const float* t = &trisA[(size_t)widx * RECA];
    float rx, ry, rz;
    float best_d2 = cp32(px, py, pz, t, rx, ry, rz);

    float abx = t[9],  aby = t[10], abz = t[11];
    float acx = t[12], acy = t[13], acz = t[14];
    float nx = (aby * acz) - (abz * acy);
    float ny = (abz * acx) - (abx * acz);
    float nz = (abx * acy) - (aby * acx);

    float dx = px - rx, dy = py - ry, dz = pz - rz;
    float sdot = ((dx * nx) + (dy * ny)) + (dz * nz);
    float sgn = (sdot >= 0.0f) ? 1.0f : -1.0f;
    float sdist = sgn * __fsqrt_rn(fmaxf(best_d2, 0.0f));

    out[q * 4 + 0] = rx;
    out[q * 4 + 1] = ry;
    out[q * 4 + 2] = rz;
    out[q * 4 + 3] = sdist;
}

// ---- prep: build exact records (verified layout) + fast records ----
__global__ void k_prep(const int* __restrict__ faces, const float* __restrict__ verts,
                       float* __restrict__ trisA, float* __restrict__ trisB, int nF)
{
#pragma clang fp contract(off)
    int i = blockIdx.x * 256 + threadIdx.x;
    if (i >= nF) return;
    int i0 = faces[i * 3 + 0], i1 = faces[i * 3 + 1], i2 = faces[i * 3 + 2];
    float ax = verts[i0 * 3], ay = verts[i0 * 3 + 1], az = verts[i0 * 3 + 2];
    float bx = verts[i1 * 3], by = verts[i1 * 3 + 1], bz = verts[i1 * 3 + 2];
    float cx = verts[i2 * 3], cy = verts[i2 * 3 + 1], cz = verts[i2 * 3 + 2];

    float abx = bx - ax, aby = by - ay, abz = bz - az;
    float acx = cx - ax, acy = cy - ay, acz = cz - az;
    float cbx = cx - bx, cby = cy - by, cbz = cz - bz;

    float* t = &trisA[(size_t)i * RECA];
    t[0]  = ax; t[1]  = ay; t[2]  = az; t[3]  = bx;
    t[4]  = by; t[5]  = bz; t[6]  = cx; t[7]  = cy;
    t[8]  = cz;
    t[9]  = abx; t[10] = aby; t[11] = abz;
    t[12] = acx; t[13] = acy; t[14] = acz;
    t[15] = cbx; t[16] = cby; t[17] = cbz;
    t[18] = 0.0f; t[19] = 0.0f;

    // fast record (approximate path -- any rounding OK)
    float aba = abx * ax + aby * ay + abz * az;
    float abb = abx * bx + aby * by + abz * bz;
    float abc = abx * cx + aby * cy + abz * cz;
    float aca = acx * ax + acy * ay + acz * az;
    float acb = acx * bx + acy * by + acz * bz;
    float acc = acx * cx + acy * cy + acz * cz;
    float aa = ax * ax + ay * ay + az * az;
    float bb = bx * bx + by * by + bz * bz;
    float ccv = cx * cx + cy * cy + cz * cz;
    float nx = aby * acz - abz * acy;
    float ny = abz * acx - abx * acz;
    float nz = abx * acy - aby * acx;
    float na = nx * ax + ny * ay + nz * az;
    float abab = abx * abx + aby * aby + abz * abz;
    float acac = acx * acx + acy * acy + acz * acz;
    float cbcb = cbx * cbx + cby * cby + cbz * cbz;
    float nn   = nx * nx + ny * ny + nz * nz;

    float* u = &trisB[(size_t)i * RECB];
    u[0]  = abx; u[1]  = aby; u[2]  = abz; u[3]  = acx;
    u[4]  = acy; u[5]  = acz; u[6]  = aba; u[7]  = abb;
    u[8]  = abc; u[9]  = aca; u[10] = acb; u[11] = acc;
    u[12] = aa;  u[13] = bb;  u[14] = ccv; u[15] = ax;
    u[16] = ay;  u[17] = az;  u[18] = nx;  u[19] = ny;
    u[20] = nz;  u[21] = na;  u[22] = 1.0f / safe32(abab);
    u[23] = 1.0f / safe32(acac);
    u[24] = 1.0f / safe32(cbcb);
    u[25] = 1.0f / safe32(nn);
    u[26] = 0.0f; u[27] = 0.0f;
}

// ---- fast scan: wave per query, faces LDS-staged; min1/min2/idx1 ----
__global__ __launch_bounds__(256) void k_scan(
    const float* __restrict__ trisB, const float* __restrict__ query,
    int* __restrict__ widx, int* __restrict__ wamb, int nF, int nQ)
{
    __shared__ float4 sB[CHUNK * (RECB / 4)];
    const int tid = threadIdx.x;
    const int lane = tid & 63;
    const int q = blockIdx.x * 4 + (tid >> 6);
    const bool valid = q < nQ;

    float px = 0.f, py = 0.f, pz = 0.f, pp = 0.f;
    if (valid) {
        px = query[q * 3]; py = query[q * 3 + 1]; pz = query[q * 3 + 2];
        pp = px * px + py * py + pz * pz;
    }

    float m1 = 3.402823466e38f, m2 = 3.402823466e38f;
    int i1 = 0x7fffffff;

    const int nchunks = (nF + CHUNK - 1) / CHUNK;
    for (int c = 0; c < nchunks; ++c) {
        const int fbase = c * CHUNK;
        const int cnt = min(CHUNK, nF - fbase);
        __syncthreads();
        {
            const float4* src = (const float4*)&trisB[(size_t)fbase * RECB];
            for (int i = tid; i < cnt * (RECB / 4); i += 256) sB[i] = src[i];
        }
        __syncthreads();
        if (!valid) continue;

#pragma unroll
        for (int it = 0; it < CHUNK / 64; ++it) {
            int j = it * 64 + lane;
            if (j >= cnt) break;
            int f = fbase + j;
            const float4* r = &sB[j * (RECB / 4)];
            float4 r0 = r[0], r1 = r[1], r2 = r[2], r3 = r[3];
            float4 r4 = r[4], r5 = r[5], r6 = r[6];
            float abx = r0.x, aby = r0.y, abz = r0.z, acx = r0.w;
            float acy = r1.x, acz = r1.y, aba = r1.z, abb = r1.w;
            float abc = r2.x, aca = r2.y, acb = r2.z, acc = r2.w;
            float aa = r3.x, bb = r3.y, cc2 = r3.z, ax = r3.w;
            float ay = r4.x, az = r4.y, nx = r4.z, ny = r4.w;
            float nz = r5.x, na = r5.y, iab = r5.z, iac = r5.w;
            float icb = r6.x, inn = r6.y;

            float abp = abx * px + aby * py + abz * pz;
            float acp = acx * px + acy * py + acz * pz;
            float apd = ax * px + ay * py + az * pz;
            float npd = nx * px + ny * py + nz * pz;
            float d1 = abp - aba, d3 = abp - abb, d5 = abp - abc;
            float d2 = acp - aca, d4 = acp - acb, d6 = acp - acc;
            float vc = d1 * d4 - d3 * d2;
            float vb = d5 * d2 - d1 * d6;
            float va = d3 * d6 - d5 * d4;
            float e1 = d4 - d3, e2 = d5 - d6;

            float bpd = apd + abp, cpd = apd + acp;
            float pap = (pp + aa) - 2.0f * apd;
            float pbp = (pp + bb) - 2.0f * bpd;
            float pcp = (pp + cc2) - 2.0f * cpd;
            float nap = npd - na;

            bool ca  = (d1 <= 0.0f) && (d2 <= 0.0f);
            bool cb_ = (d3 >= 0.0f) && (d4 <= d3);
            bool cab = (vc <= 0.0f) && (d1 >= 0.0f) && (d3 <= 0.0f);
            bool cc_ = (d6 >= 0.0f) && (d5 <= d6);
            bool cac = (vb <= 0.0f) && (d2 >= 0.0f) && (d6 <= 0.0f);
            bool cbc = (va <= 0.0f) && (e1 >= 0.0f) && (e2 >= 0.0f);
            bool tk  = ca;
            bool m_b  = cb_ && !tk;  tk = tk || cb_;
            bool m_ab = cab && !tk;  tk = tk || cab;
            bool m_c  = cc_ && !tk;  tk = tk || cc_;
            bool m_ac = cac && !tk;  tk = tk || cac;
            bool m_bc = cbc && !tk;  tk = tk || cbc;
            bool m_in = !tk;

            float base = m_c ? pcp : (m_b || m_bc) ? pbp : pap;
            float num  = m_ab ? d1 : m_ac ? d2 : m_bc ? e1 : nap;
            float inv  = m_ab ? iab : m_ac ? iac : m_bc ? icb : inn;
            bool corr_on = m_ab || m_ac || m_bc || m_in;
            float tcorr = corr_on ? (num * num) * inv : 0.0f;
            float d2a = m_in ? tcorr : (base - tcorr);

            if (d2a < m1) { m2 = m1; m1 = d2a; i1 = f; }
            else m2 = fminf(m2, d2a);
        }
    }

    if (!valid) return;
    // reduce (m1,i1,m2) across the wave
    for (int o = 32; o > 0; o >>= 1) {
        float om1 = __shfl_down(m1, o);
        int   oi1 = __shfl_down(i1, o);
        float om2 = __shfl_down(m2, o);
        float hi = fmaxf(m1, om1);
        m2 = fminf(fminf(m2, om2), hi);
        bool take = (om1 < m1) || (om1 == m1 && oi1 < i1);
        if (take) { m1 = om1; i1 = oi1; }
    }
    if (lane == 0) {
        float margin = 1e-3f * (1.0f + m1);
        widx[q] = i1;
        wamb[q] = (m2 <= m1 + margin) ? 1 : 0;
    }
}

// ---- final: unambiguous -> exact epilogue; ambiguous -> exact full scan ----
__global__ __launch_bounds__(256) void k_final(
    const float* __restrict__ trisA, const float* __restrict__ query,
    const int* __restrict__ widx, const int* __restrict__ wamb,
    float* __restrict__ out, int nF, int nQ)
{
    const int q = blockIdx.x * 4 + (threadIdx.x >> 6);
    const int lane = threadIdx.x & 63;
    if (q >= nQ) return;

    const float px = query[q * 3], py = query[q * 3 + 1], pz = query[q * 3 + 2];

    if (!wamb[q]) {
        if (lane == 0) write_result(q, widx[q], trisA, px, py, pz, out);
        return;
    }

    // exact full rescan (verified R4 structure): lane-strided + lexicographic
    float best = 3.402823466e38f;
    int bidx = 0x7fffffff;
    for (int f = lane; f < nF; f += 64) {
        float rx, ry, rz;
        float d2 = cp32(px, py, pz, &trisA[(size_t)f * RECA], rx, ry, rz);
        if (d2 < best) { best = d2; bidx = f; }   // ascending f: first occurrence
    }
    for (int o = 32; o > 0; o >>= 1) {
        float od = __shfl_down(best, o);
        int   oi = __shfl_down(bidx, o);
        if (od < best || (od == best && oi < bidx)) { best = od; bidx = oi; }
    }
    if (lane == 0) write_result(q, bidx, trisA, px, py, pz, out);
}

extern "C" void kernel_launch(void* const* d_in, const int* in_sizes, int n_in,
                              void* d_out, int out_size, void* d_ws, size_t ws_size,
                              hipStream_t stream) {
    const int* faces = (const int*)d_in[0];
    const float* verts = (const float*)d_in[1];
    const float* query = (const float*)d_in[2];
    float* out = (float*)d_out;

    const int nF = in_sizes[0] / 3;
    const int nQ = in_sizes[2] / 3;

    char* ws = (char*)d_ws;
    float* trisA = (float*)ws;                                   // nF*20 f
    float* trisB = (float*)(ws + (size_t)nF * RECA * 4);         // nF*28 f
    int* widx = (int*)(ws + (size_t)nF * (RECA + RECB) * 4);     // nQ int
    int* wamb = widx + nQ;                                       // nQ int

    k_prep<<<(nF + 255) / 256, 256, 0, stream>>>(faces, verts, trisA, trisB, nF);

    int qblocks = (nQ + 3) / 4;   // wave per query
    k_scan<<<qblocks, 256, 0, stream>>>(trisB, query, widx, wamb, nF, nQ);
    k_final<<<qblocks, 256, 0, stream>>>(trisA, query, widx, wamb, out, nF, nQ);
}

// Round 8
// 170.289 us; speedup vs baseline: 1.1173x; 1.1173x over previous
//
#include <hip/hip_runtime.h>
#include <stdint.h>

// SDF closest-point + signed distance, 8192 queries x 2048 tris.
//
// Verified correctness model (R4-R6): harness ref = numpy float32 faithful
// chain; strict IEEE f32, NO fma contraction (pragma inside function), numpy
// op order, np.argmin first-occurrence. cp32 below is the verified DAG.
//
// R8 = R7 filter-then-verify with two fixes:
//  - component-major LDS (sB[7][CHUNK]) -> contiguous-b128 reads, no 8-way
//    bank conflicts (R7: 112B AoS stride, 1.7e7 conflicts).
//  - margin tightened to 3e-4 + 1e-4*m1 (approx abs error <= ~7e-5) vs 1e-3,
//    cutting the exact-rescan fraction ~30x.
// Fast-path d2a region formulas (exact-math equivalent):
//   a/b/c: |p-v|^2 ; ab: pap - d1^2/|ab|^2 ; ac: pap - d2^2/|ac|^2 ;
//   bc: pbp - e1^2/|cb|^2 ; interior: (n.ap)^2/|n|^2.

#define RECA 20   // exact record: a,b,c,ab,ac,cb,pad2
#define CHUNK 256 // faces per LDS chunk in k_scan
#define SQPB 512  // k_scan threads (8 wave-queries per block)

__device__ __forceinline__ float safe32(float x) {
    return (fabsf(x) < 1e-12f) ? 1e-12f : x;
}

// ---- exact path (verified bit-exact vs np-f32 in R4/R5/R6) ----
__device__ __forceinline__ float cp32(
    float px, float py, float pz, const float* __restrict__ t,
    float& rx, float& ry, float& rz)
{
#pragma clang fp contract(off)
    float ax  = t[0],  ay  = t[1],  az  = t[2];
    float bx  = t[3],  by  = t[4],  bz  = t[5];
    float cx  = t[6],  cy  = t[7],  cz  = t[8];
    float abx = t[9],  aby = t[10], abz = t[11];
    float acx = t[12], acy = t[13], acz = t[14];
    float cbx = t[15], cby = t[16], cbz = t[17];

    float apx = px - ax, apy = py - ay, apz = pz - az;
    float bpx = px - bx, bpy = py - by, bpz = pz - bz;
    float qpx = px - cx, qpy = py - cy, qpz = pz - cz;

    float d1 = ((abx * apx) + (aby * apy)) + (abz * apz);
    float d2 = ((acx * apx) + (acy * apy)) + (acz * apz);
    float d3 = ((abx * bpx) + (aby * bpy)) + (abz * bpz);
    float d4 = ((acx * bpx) + (acy * bpy)) + (acz * bpz);
    float d5 = ((abx * qpx) + (aby * qpy)) + (abz * qpz);
    float d6 = ((acx * qpx) + (acy * qpy)) + (acz * qpz);

    float vc = (d1 * d4) - (d3 * d2);
    float vb = (d5 * d2) - (d1 * d6);
    float va = (d3 * d6) - (d5 * d4);
    float e1 = d4 - d3;
    float e2 = d5 - d6;

    bool ca  = (d1 <= 0.0f) && (d2 <= 0.0f);
    bool cb_ = (d3 >= 0.0f) && (d4 <= d3);
    bool cab = (vc <= 0.0f) && (d1 >= 0.0f) && (d3 <= 0.0f);
    bool cc_ = (d6 >= 0.0f) && (d5 <= d6);
    bool cac = (vb <= 0.0f) && (d2 >= 0.0f) && (d6 <= 0.0f);
    bool cbc = (va <= 0.0f) && (e1 >= 0.0f) && (e2 >= 0.0f);

    bool tk  = ca;
    bool m_b  = cb_ && !tk;  tk = tk || cb_;
    bool m_ab = cab && !tk;  tk = tk || cab;
    bool m_c  = cc_ && !tk;  tk = tk || cc_;
    bool m_ac = cac && !tk;  tk = tk || cac;
    bool m_bc = cbc && !tk;  tk = tk || cbc;
    bool m_in = !tk;

    float denom_raw = (va + vb) + vc;
    float num1 = m_ab ? d1 : m_ac ? d2 : m_bc ? e1 : m_in ? vb : 0.0f;
    float den1_raw = m_ab ? (d1 - d3) : m_ac ? (d2 - d6)
                   : m_bc ? (e1 + e2) : m_in ? denom_raw : 1.0f;
    float den1  = safe32(den1_raw);
    float denom = safe32(denom_raw);
    float num2  = m_in ? vc : 0.0f;
    float q1 = num1 / den1;
    float q2 = num2 / denom;

    bool sel_b = m_b || m_bc;
    float basx = m_c ? cx : sel_b ? bx : ax;
    float basy = m_c ? cy : sel_b ? by : ay;
    float basz = m_c ? cz : sel_b ? bz : az;

    bool s_ab = m_ab || m_in;
    float t1x = m_bc ? cbx : m_ac ? acx : s_ab ? abx : 0.0f;
    float t1y = m_bc ? cby : m_ac ? acy : s_ab ? aby : 0.0f;
    float t1z = m_bc ? cbz : m_ac ? acz : s_ab ? abz : 0.0f;

    float t2x = m_in ? acx : 0.0f;
    float t2y = m_in ? acy : 0.0f;
    float t2z = m_in ? acz : 0.0f;

    rx = (basx + (t1x * q1)) + (t2x * q2);
    ry = (basy + (t1y * q1)) + (t2y * q2);
    rz = (basz + (t1z * q1)) + (t2z * q2);

    float dx = px - rx, dy = py - ry, dz = pz - rz;
    return ((dx * dx) + (dy * dy)) + (dz * dz);
}

// Exact epilogue (verified): recompute winner, normal, sign, write.
__device__ __forceinline__ void write_result(
    int q, int widx, const float* __restrict__ trisA,
    float px, float py, float pz, float* __restrict__ out)
{
#pragma clang fp contract(off)
    const float* t = &trisA[(size_t)widx * RECA];
    float rx, ry, rz;
    float best_d2 = cp32(px, py, pz, t, rx, ry, rz);

    float abx = t[9],  aby = t[10], abz = t[11];
    float acx = t[12], acy = t[13], acz = t[14];
    float nx = (aby * acz) - (abz * acy);
    float ny = (abz * acx) - (abx * acz);
    float nz = (abx * acy) - (aby * acx);

    float dx = px - rx, dy = py - ry, dz = pz - rz;
    float sdot = ((dx * nx) + (dy * ny)) + (dz * nz);
    float sgn = (sdot >= 0.0f) ? 1.0f : -1.0f;
    float sdist = sgn * __fsqrt_rn(fmaxf(best_d2, 0.0f));

    out[q * 4 + 0] = rx;
    out[q * 4 + 1] = ry;
    out[q * 4 + 2] = rz;
    out[q * 4 + 3] = sdist;
}

// ---- prep: exact records (verified layout) + fast records (7x float4) ----
// fast rec: r0=(abx,aby,abz,acx) r1=(acy,acz,aba,abb) r2=(abc,aca,acb,acc)
//           r3=(aa,bb,cc,ax)     r4=(ay,az,nx,ny)     r5=(nz,na,iab,iac)
//           r6=(icb,inn,0,0)
__global__ void k_prep(const int* __restrict__ faces, const float* __restrict__ verts,
                       float* __restrict__ trisA, float4* __restrict__ trisB, int nF)
{
#pragma clang fp contract(off)
    int i = blockIdx.x * 256 + threadIdx.x;
    if (i >= nF) return;
    int i0 = faces[i * 3 + 0], i1 = faces[i * 3 + 1], i2 = faces[i * 3 + 2];
    float ax = verts[i0 * 3], ay = verts[i0 * 3 + 1], az = verts[i0 * 3 + 2];
    float bx = verts[i1 * 3], by = verts[i1 * 3 + 1], bz = verts[i1 * 3 + 2];
    float cx = verts[i2 * 3], cy = verts[i2 * 3 + 1], cz = verts[i2 * 3 + 2];

    float abx = bx - ax, aby = by - ay, abz = bz - az;
    float acx = cx - ax, acy = cy - ay, acz = cz - az;
    float cbx = cx - bx, cby = cy - by, cbz = cz - bz;

    float* t = &trisA[(size_t)i * RECA];
    t[0]  = ax; t[1]  = ay; t[2]  = az; t[3]  = bx;
    t[4]  = by; t[5]  = bz; t[6]  = cx; t[7]  = cy;
    t[8]  = cz;
    t[9]  = abx; t[10] = aby; t[11] = abz;
    t[12] = acx; t[13] = acy; t[14] = acz;
    t[15] = cbx; t[16] = cby; t[17] = cbz;
    t[18] = 0.0f; t[19] = 0.0f;

    float aba = abx * ax + aby * ay + abz * az;
    float abb = abx * bx + aby * by + abz * bz;
    float abc = abx * cx + aby * cy + abz * cz;
    float aca = acx * ax + acy * ay + acz * az;
    float acb = acx * bx + acy * by + acz * bz;
    float acc = acx * cx + acy * cy + acz * cz;
    float aa = ax * ax + ay * ay + az * az;
    float bb = bx * bx + by * by + bz * bz;
    float ccv = cx * cx + cy * cy + cz * cz;
    float nx = aby * acz - abz * acy;
    float ny = abz * acx - abx * acz;
    float nz = abx * acy - aby * acx;
    float na = nx * ax + ny * ay + nz * az;
    float abab = abx * abx + aby * aby + abz * abz;
    float acac = acx * acx + acy * acy + acz * acz;
    float cbcb = cbx * cbx + cby * cby + cbz * cbz;
    float nn   = nx * nx + ny * ny + nz * nz;

    float4* u = &trisB[(size_t)i * 7];
    u[0] = make_float4(abx, aby, abz, acx);
    u[1] = make_float4(acy, acz, aba, abb);
    u[2] = make_float4(abc, aca, acb, acc);
    u[3] = make_float4(aa, bb, ccv, ax);
    u[4] = make_float4(ay, az, nx, ny);
    u[5] = make_float4(nz, na, 1.0f / safe32(abab), 1.0f / safe32(acac));
    u[6] = make_float4(1.0f / safe32(cbcb), 1.0f / safe32(nn), 0.0f, 0.0f);
}

// ---- fast scan: 8 wave-queries/block, component-major LDS, min1/min2 ----
__global__ __launch_bounds__(SQPB) void k_scan(
    const float4* __restrict__ trisB, const float* __restrict__ query,
    int* __restrict__ widx, int* __restrict__ wamb, int nF, int nQ)
{
    __shared__ float4 sB[7][CHUNK];        // component-major: lane j -> sB[c][j]
    const int tid = threadIdx.x;
    const int lane = tid & 63;
    const int q = blockIdx.x * (SQPB / 64) + (tid >> 6);
    const bool valid = q < nQ;

    float px = 0.f, py = 0.f, pz = 0.f, pp = 0.f;
    if (valid) {
        px = query[q * 3]; py = query[q * 3 + 1]; pz = query[q * 3 + 2];
        pp = px * px + py * py + pz * pz;
    }

    float m1 = 3.402823466e38f, m2 = 3.402823466e38f;
    int i1 = 0x7fffffff;

    const int nchunks = (nF + CHUNK - 1) / CHUNK;
    for (int c = 0; c < nchunks; ++c) {
        const int fbase = c * CHUNK;
        const int cnt = min(CHUNK, nF - fbase);
        __syncthreads();
        {   // coalesced global float4 reads, transposed LDS writes
            const float4* src = &trisB[(size_t)fbase * 7];
            for (int i = tid; i < cnt * 7; i += SQPB) {
                int f = i / 7, comp = i - f * 7;
                sB[comp][f] = src[i];
            }
        }
        __syncthreads();
        if (!valid) continue;

#pragma unroll
        for (int it = 0; it < CHUNK / 64; ++it) {
            int j = it * 64 + lane;
            if (j >= cnt) break;
            int f = fbase + j;
            float4 r0 = sB[0][j], r1 = sB[1][j], r2 = sB[2][j], r3 = sB[3][j];
            float4 r4 = sB[4][j], r5 = sB[5][j], r6 = sB[6][j];
            float abx = r0.x, aby = r0.y, abz = r0.z, acx = r0.w;
            float acy = r1.x, acz = r1.y, aba = r1.z, abb = r1.w;
            float abc = r2.x, aca = r2.y, acb = r2.z, acc = r2.w;
            float aa = r3.x, bb = r3.y, cc2 = r3.z, ax = r3.w;
            float ay = r4.x, az = r4.y, nx = r4.z, ny = r4.w;
            float nz = r5.x, na = r5.y, iab = r5.z, iac = r5.w;
            float icb = r6.x, inn = r6.y;

            float abp = abx * px + aby * py + abz * pz;
            float acp = acx * px + acy * py + acz * pz;
            float apd = ax * px + ay * py + az * pz;
            float npd = nx * px + ny * py + nz * pz;
            float d1 = abp - aba, d3 = abp - abb, d5 = abp - abc;
            float d2 = acp - aca, d4 = acp - acb, d6 = acp - acc;
            float vc = d1 * d4 - d3 * d2;
            float vb = d5 * d2 - d1 * d6;
            float va = d3 * d6 - d5 * d4;
            float e1 = d4 - d3, e2 = d5 - d6;

            float bpd = apd + abp, cpd = apd + acp;
            float pap = (pp + aa) - 2.0f * apd;
            float pbp = (pp + bb) - 2.0f * bpd;
            float pcp = (pp + cc2) - 2.0f * cpd;
            float nap = npd - na;

            bool ca  = (d1 <= 0.0f) && (d2 <= 0.0f);
            bool cb_ = (d3 >= 0.0f) && (d4 <= d3);
            bool cab = (vc <= 0.0f) && (d1 >= 0.0f) && (d3 <= 0.0f);
            bool cc_ = (d6 >= 0.0f) && (d5 <= d6);
            bool cac = (vb <= 0.0f) && (d2 >= 0.0f) && (d6 <= 0.0f);
            bool cbc = (va <= 0.0f) && (e1 >= 0.0f) && (e2 >= 0.0f);
            bool tk  = ca;
            bool m_b  = cb_ && !tk;  tk = tk || cb_;
            bool m_ab = cab && !tk;  tk = tk || cab;
            bool m_c  = cc_ && !tk;  tk = tk || cc_;
            bool m_ac = cac && !tk;  tk = tk || cac;
            bool m_bc = cbc && !tk;  tk = tk || cbc;
            bool m_in = !tk;

            float base = m_c ? pcp : (m_b || m_bc) ? pbp : pap;
            float num  = m_ab ? d1 : m_ac ? d2 : m_bc ? e1 : nap;
            float inv  = m_ab ? iab : m_ac ? iac : m_bc ? icb : inn;
            bool corr_on = m_ab || m_ac || m_bc || m_in;
            float tcorr = corr_on ? (num * num) * inv : 0.0f;
            float d2a = m_in ? tcorr : (base - tcorr);

            if (d2a < m1) { m2 = m1; m1 = d2a; i1 = f; }
            else m2 = fminf(m2, d2a);
        }
    }

    if (!valid) return;
    for (int o = 32; o > 0; o >>= 1) {
        float om1 = __shfl_down(m1, o);
        int   oi1 = __shfl_down(i1, o);
        float om2 = __shfl_down(m2, o);
        float hi = fmaxf(m1, om1);
        m2 = fminf(fminf(m2, om2), hi);
        bool take = (om1 < m1) || (om1 == m1 && oi1 < i1);
        if (take) { m1 = om1; i1 = oi1; }
    }
    if (lane == 0) {
        // |d2a - d2exact| <= ~7e-5 abs (operands <= ~60, ~8 rounding ops);
        // margin >= 2E with headroom. Certificate: m2 > m1 + margin ->
        // i1 is the unique exact argmin.
        float margin = 3e-4f + 1e-4f * m1;
        widx[q] = i1;
        wamb[q] = (m2 <= m1 + margin) ? 1 : 0;
    }
}

// ---- final: unambiguous -> exact epilogue; ambiguous -> exact full scan ----
__global__ __launch_bounds__(256) void k_final(
    const float* __restrict__ trisA, const float* __restrict__ query,
    const int* __restrict__ widx, const int* __restrict__ wamb,
    float* __restrict__ out, int nF, int nQ)
{
    const int q = blockIdx.x * 4 + (threadIdx.x >> 6);
    const int lane = threadIdx.x & 63;
    if (q >= nQ) return;

    const float px = query[q * 3], py = query[q * 3 + 1], pz = query[q * 3 + 2];

    if (!wamb[q]) {
        if (lane == 0) write_result(q, widx[q], trisA, px, py, pz, out);
        return;
    }

    // exact full rescan (verified R4 structure): lane-strided + lexicographic
    float best = 3.402823466e38f;
    int bidx = 0x7fffffff;
    for (int f = lane; f < nF; f += 64) {
        float rx, ry, rz;
        float d2 = cp32(px, py, pz, &trisA[(size_t)f * RECA], rx, ry, rz);
        if (d2 < best) { best = d2; bidx = f; }   // ascending f: first occurrence
    }
    for (int o = 32; o > 0; o >>= 1) {
        float od = __shfl_down(best, o);
        int   oi = __shfl_down(bidx, o);
        if (od < best || (od == best && oi < bidx)) { best = od; bidx = oi; }
    }
    if (lane == 0) write_result(q, bidx, trisA, px, py, pz, out);
}

extern "C" void kernel_launch(void* const* d_in, const int* in_sizes, int n_in,
                              void* d_out, int out_size, void* d_ws, size_t ws_size,
                              hipStream_t stream) {
    const int* faces = (const int*)d_in[0];
    const float* verts = (const float*)d_in[1];
    const float* query = (const float*)d_in[2];
    float* out = (float*)d_out;

    const int nF = in_sizes[0] / 3;
    const int nQ = in_sizes[2] / 3;

    char* ws = (char*)d_ws;
    float* trisA = (float*)ws;                                   // nF*20 f32
    float4* trisB = (float4*)(ws + (size_t)nF * RECA * 4);       // nF*7 float4
    int* widx = (int*)(ws + (size_t)nF * (RECA + 28) * 4);       // nQ int
    int* wamb = widx + nQ;                                       // nQ int

    k_prep<<<(nF + 255) / 256, 256, 0, stream>>>(faces, verts, trisA, trisB, nF);

    int sblocks = (nQ + (SQPB / 64) - 1) / (SQPB / 64);
    k_scan<<<sblocks, SQPB, 0, stream>>>(trisB, query, widx, wamb, nF, nQ);

    int fblocks = (nQ + 3) / 4;
    k_final<<<fblocks, 256, 0, stream>>>(trisA, query, widx, wamb, out, nF, nQ);
}